// Round 5
// baseline (276.367 us; speedup 1.0000x reference)
//
#include <hip/hip_runtime.h>

#define BB 64
#define NN 3000
#define MM 128
#define NBINS 1280
#define NSEL 128
#define TILES 12                  // 12*256 = 3072 >= 3000 rois
#define CBLK (BB * TILES)         // 768 compute blocks
#define ZBLK 1024                 // zero-fill blocks
#define TOTB (CBLK + ZBLK)        // 1792 total blocks
#define OUT4 (BB * NN * 21 * 5 / 4)  // 5,040,000 float4 = all of d_out

// One fused kernel. Roles by blockIdx.x:
//   [0, CBLK)      : IoU/argmax/deltas/packed for (b = bid/12, tile = bid%12)
//   [CBLK, TOTB)   : grid-stride zero-fill of ALL of d_out
// All blocks arrive at a device-scope counter; blocks [0, BB) then wait and
// run per-batch top-128 selection + sparse scatter into the zeroed output.
// packed[n] = posmult(11b) | negmult(11b)<<11 | gtlabel(5b)<<22
__global__ __launch_bounds__(256) void k_fused(
    const float4* __restrict__ roi, const float4* __restrict__ gt,
    const int* __restrict__ gtl, const int* __restrict__ rpos,
    const int* __restrict__ rneg, int* __restrict__ packed,
    float4* __restrict__ deltas, float4* __restrict__ out1,
    float* __restrict__ out2, unsigned* __restrict__ cnt)
{
  #pragma clang fp contract(off)
  const int tid = threadIdx.x;
  const int bid = blockIdx.x;
  __shared__ __align__(16) char smem[17200];

  if (bid < CBLK) {
    // ---------------- compute role ----------------
    float4* g  = (float4*)smem;            // 2048 B
    float*  ga = (float*)(smem + 2048);    // 512 B
    int*    gl = (int*)(smem + 2560);      // 512 B
    const int b = bid / TILES;
    const int n = (bid % TILES) * 256 + tid;
    const bool valid = (n < NN);

    float4 r = roi[b * NN + (valid ? n : 0)];
    if (tid < MM) {
      float4 v = gt[b * MM + tid];
      g[tid]  = v;
      ga[tid] = (v.z - v.x) * (v.w - v.y);
      gl[tid] = gtl[b * MM + tid];
    }
    __syncthreads();

    if (valid) {
      float ar = (r.z - r.x) * (r.w - r.y);
      float best = -1.0f; int bi = 0;
      #pragma unroll 4
      for (int m = 0; m < MM; ++m) {
        float4 gm = g[m];
        float iy1 = fmaxf(r.x, gm.x);
        float ix1 = fmaxf(r.y, gm.y);
        float iy2 = fminf(r.z, gm.z);
        float ix2 = fminf(r.w, gm.w);
        float inter = fmaxf(iy2 - iy1, 0.0f) * fmaxf(ix2 - ix1, 0.0f);
        float iou = inter / (ar + ga[m] - inter + 1e-7f);  // IEEE div = np
        if (iou > best) { best = iou; bi = m; }  // strict > = first argmax
      }
      int pm = (best > 0.5f) ? rpos[b * NN + n] : 0;
      int nm = (best < 0.5f && best > 0.1f) ? rneg[b * NN + n] : 0;
      packed[b * NN + n] = pm | (nm << 11) | (gl[bi] << 22);

      float4 gg = g[bi];
      float bw = r.w - r.y, bh = r.z - r.x;
      float bcx = r.y + 0.5f * bw, bcy = r.x + 0.5f * bh;
      float gw = gg.w - gg.y, gh = gg.z - gg.x;
      float gcx = gg.y + 0.5f * gw, gcy = gg.x + 0.5f * gh;
      bw = (bw == 0.0f) ? 0.001f : bw;
      bh = (bh == 0.0f) ? 0.001f : bh;
      float dx = (gw == 0.0f) ? 0.0f : (gcx - bcx) / bw;
      float dy = (gh == 0.0f) ? 0.0f : (gcy - bcy) / bh;
      float dw = (gw == 0.0f) ? 0.0f : logf(gw / bw);
      float dh = (gh == 0.0f) ? 0.0f : logf(gh / bh);
      deltas[b * NN + n] = make_float4(dy / 0.1f, dx / 0.1f, dh / 0.2f, dw / 0.2f);
    }
  } else {
    // ---------------- zero role: stream zeros over all of d_out ----------
    const float4 z = make_float4(0.f, 0.f, 0.f, 0.f);
    float4* o = (float4*)out1;   // out1 is the base of d_out
    for (int i = (bid - CBLK) * 256 + tid; i < OUT4; i += ZBLK * 256)
      o[i] = z;
  }

  // ---------------- device-scope arrive ----------------
  __threadfence();   // make this thread's global stores visible device-wide
  __syncthreads();   // whole block arrived + fenced
  if (tid == 0)
    __hip_atomic_fetch_add(cnt, 1u, __ATOMIC_RELEASE, __HIP_MEMORY_SCOPE_AGENT);
  if (bid >= BB) return;

  // ---------------- wait (only 64 blocks) ----------------
  if (tid == 0) {
    while (__hip_atomic_load(cnt, __ATOMIC_ACQUIRE, __HIP_MEMORY_SCOPE_AGENT)
           < (unsigned)TOTB)
      __builtin_amdgcn_s_sleep(8);
  }
  __syncthreads();

  // ---------------- selection role: batch b = bid ----------------
  const int b = bid;
  const int lane = tid & 63;
  const int wave = tid >> 6;
  int*      sp   = (int*)smem;                   // 12000 B
  unsigned* hist = (unsigned*)(smem + 12032);    // 5124 B (NBINS+1)
  unsigned* wsum = (unsigned*)(smem + 17168);    // 16 B
  int*      sT   = (int*)(smem + 17184);         // 16 B: Tp,Qp,Tn,Qn

  for (int i = tid; i < NBINS + 1; i += 256) hist[i] = 0;
  if (tid < 4) sT[tid] = 0;
  __syncthreads();

  for (int i = tid; i < NN; i += 256) {
    int p = packed[b * NN + i];
    sp[i] = p;
    int pm = p & 0x7FF, nm = (p >> 11) & 0x7FF;
    if (pm) atomicAdd(&hist[pm], 1u);
    if (nm) atomicAdd(&hist[nm], 0x10000u);
  }
  __syncthreads();

  // single-wave register suffix scan over 1280 bins (20 bins/lane, packed)
  if (wave == 0) {
    unsigned cs[21];
    const int base = 1 + lane * 20;
    cs[20] = 0;
    #pragma unroll
    for (int j = 19; j >= 0; --j) cs[j] = cs[j + 1] + hist[base + j];
    unsigned tot = cs[0];
    unsigned run = tot;
    #pragma unroll
    for (int off = 1; off < 64; off <<= 1) {
      unsigned u = __shfl_down(run, off);
      if (lane + off < 64) run += u;
    }
    unsigned above = run - tot;  // suffix over lanes > lane
    #pragma unroll
    for (int j = 0; j < 20; ++j) {
      int bin = base + j;
      unsigned s  = cs[j] + above;
      unsigned sn = cs[j + 1] + above;
      unsigned ps = s & 0xFFFFu, psn = sn & 0xFFFFu;
      if (ps >= NSEL && psn < NSEL) { sT[0] = bin; sT[1] = NSEL - (int)psn; }
      unsigned ns = s >> 16, nsn = sn >> 16;
      if (ns >= NSEL && nsn < NSEL) { sT[2] = bin; sT[3] = NSEL - (int)nsn; }
    }
  }
  __syncthreads();
  const int Tp = sT[0], Qp = sT[1], Tn = sT[2], Qn = sT[3];

  // tie-rank: thread t owns contiguous chunk [12t, 12t+12)
  const int n0 = tid * 12;
  int q[12];
  #pragma unroll
  for (int j = 0; j < 12; ++j) {
    int n = n0 + j;
    q[j] = (n < NN) ? sp[n] : 0;
  }
  unsigned cc = 0;
  #pragma unroll
  for (int j = 0; j < 12; ++j) {
    int pm = q[j] & 0x7FF, nm = (q[j] >> 11) & 0x7FF;
    if (Tp && pm == Tp) cc += 1u;
    if (Tn && nm == Tn) cc += 0x10000u;
  }
  unsigned inc = cc;
  #pragma unroll
  for (int off = 1; off < 64; off <<= 1) {
    unsigned u = __shfl_up(inc, off);
    if (lane >= off) inc += u;
  }
  if (lane == 63) wsum[wave] = inc;
  __syncthreads();
  unsigned woff = 0;
  for (int w = 0; w < wave; ++w) woff += wsum[w];
  unsigned excl = woff + (inc - cc);
  int ep = (int)(excl & 0xFFFFu), en = (int)(excl >> 16);

  // selection + sparse scatter into pre-zeroed outputs
  #pragma unroll
  for (int j = 0; j < 12; ++j) {
    int n = n0 + j;
    if (n >= NN) break;
    int p = q[j];
    int pm = p & 0x7FF, nm = (p >> 11) & 0x7FF;
    bool selp;
    if (pm > Tp) selp = true;
    else if (pm && pm == Tp) { selp = (ep < Qp); ep++; }
    else selp = false;
    bool seln;
    if (nm > Tn) seln = true;
    else if (nm && nm == Tn) { seln = (en < Qn); en++; }
    else seln = false;
    if (selp | seln) {
      size_t nl = (size_t)b * NN + n;
      int lab = selp ? ((p >> 22) & 0x1F) : 0;
      out2[nl * 21 + lab] = 1.0f;
      if (lab > 0) out1[nl * 21 + lab] = deltas[nl];
    }
  }
}

extern "C" void kernel_launch(void* const* d_in, const int* in_sizes, int n_in,
                              void* d_out, int out_size, void* d_ws, size_t ws_size,
                              hipStream_t stream) {
  const float4* roi = (const float4*)d_in[0];
  const float4* gt  = (const float4*)d_in[1];
  const int* gtl  = (const int*)d_in[2];
  const int* rpos = (const int*)d_in[3];
  const int* rneg = (const int*)d_in[4];

  char* ws = (char*)d_ws;
  int*      packed = (int*)ws;                   // B*N ints (768 KB)
  float4*   deltas = (float4*)(ws + (1 << 20));  // B*N float4 (3 MB)
  unsigned* cnt    = (unsigned*)(ws + (8 << 20));

  float4* out1 = (float4*)d_out;                            // B*N*21 float4
  float*  out2 = (float*)d_out + (size_t)BB * NN * 21 * 4;  // B*N*21 floats

  hipMemsetAsync(cnt, 0, sizeof(unsigned), stream);
  k_fused<<<TOTB, 256, 0, stream>>>(roi, gt, gtl, rpos, rneg, packed, deltas,
                                    out1, out2, cnt);
}

// Round 6
// 47.015 us; speedup vs baseline: 5.8783x; 5.8783x over previous
//
#include <hip/hip_runtime.h>

#define BB 64
#define NN 3000
#define MM 128
#define NBINS 1280
#define NSEL 128
#define ZB 1024          // zero-fill blocks (blocks [0, ZB) )
#define CB (BB * 12)     // compute blocks   (blocks [ZB, ZB+CB) ), 12 tiles/batch

// ---------------- Kernel A: fused zero-fill + IoU/argmax/deltas/packed -------
// Block roles: [0,ZB) stream zeros over ALL of d_out (grid-stride, many
// stores/thread); [ZB, ZB+CB) compute per-roi packed masks + deltas.
// packed[n] = posmult(11b) | negmult(11b)<<11 | gtlabel(5b)<<22
__global__ __launch_bounds__(256) void kA(
    const float4* __restrict__ roi, const float4* __restrict__ gt,
    const int* __restrict__ gtl, const int* __restrict__ rpos,
    const int* __restrict__ rneg, int* __restrict__ packed,
    float4* __restrict__ deltas, float4* __restrict__ outz)
{
  #pragma clang fp contract(off)
  const int tid = threadIdx.x;

  if (blockIdx.x < ZB) {
    // ---- zero role: 5,040,000 float4 over 262,144 threads = ~19 stores each
    const float4 z = make_float4(0.f, 0.f, 0.f, 0.f);
    const int total4 = BB * NN * 21 * 5 / 4;     // 5,040,000
    for (int i = blockIdx.x * 256 + tid; i < total4; i += ZB * 256)
      outz[i] = z;
    return;
  }

  // ---- compute role
  const int cb = blockIdx.x - ZB;
  const int b = cb / 12;
  const int n = (cb % 12) * 256 + tid;
  const bool valid = (n < NN);
  __shared__ float4 g[MM];
  __shared__ float  ga[MM];
  __shared__ int    gl[MM];

  float4 r = roi[b * NN + (valid ? n : 0)];
  if (tid < MM) {
    float4 v = gt[b * MM + tid];
    g[tid]  = v;
    ga[tid] = (v.z - v.x) * (v.w - v.y);
    gl[tid] = gtl[b * MM + tid];
  }
  __syncthreads();
  if (!valid) return;

  float ar = (r.z - r.x) * (r.w - r.y);
  float best = -1.0f; int bi = 0;
  #pragma unroll 4
  for (int m = 0; m < MM; ++m) {
    float4 gm = g[m];
    float iy1 = fmaxf(r.x, gm.x);
    float ix1 = fmaxf(r.y, gm.y);
    float iy2 = fminf(r.z, gm.z);
    float ix2 = fminf(r.w, gm.w);
    float inter = fmaxf(iy2 - iy1, 0.0f) * fmaxf(ix2 - ix1, 0.0f);
    float iou = inter / (ar + ga[m] - inter + 1e-7f);  // IEEE div = np bitwise
    if (iou > best) { best = iou; bi = m; }            // strict > = first argmax
  }
  int pm = (best > 0.5f) ? rpos[b * NN + n] : 0;
  int nm = (best < 0.5f && best > 0.1f) ? rneg[b * NN + n] : 0;
  packed[b * NN + n] = pm | (nm << 11) | (gl[bi] << 22);

  float4 gg = g[bi];
  float bw = r.w - r.y, bh = r.z - r.x;
  float bcx = r.y + 0.5f * bw, bcy = r.x + 0.5f * bh;
  float gw = gg.w - gg.y, gh = gg.z - gg.x;
  float gcx = gg.y + 0.5f * gw, gcy = gg.x + 0.5f * gh;
  bw = (bw == 0.0f) ? 0.001f : bw;
  bh = (bh == 0.0f) ? 0.001f : bh;
  float dx = (gw == 0.0f) ? 0.0f : (gcx - bcx) / bw;
  float dy = (gh == 0.0f) ? 0.0f : (gcy - bcy) / bh;
  float dw = (gw == 0.0f) ? 0.0f : logf(gw / bw);
  float dh = (gh == 0.0f) ? 0.0f : logf(gh / bh);
  deltas[b * NN + n] = make_float4(dy / 0.1f, dx / 0.1f, dh / 0.2f, dw / 0.2f);
}

// ---------------- Kernel B: top-128 selection + SPARSE scatter ---------------
// rank = position in stable descending sort of mask*rand; selected iff
// masked && rank < 128 (ties by lowest index). Scatters <=256 nonzeros
// per batch into the pre-zeroed outputs.
__global__ __launch_bounds__(1024) void kB(
    const int* __restrict__ packed, const float4* __restrict__ deltas,
    float4* __restrict__ out1, float* __restrict__ out2)
{
  const int b = blockIdx.x;
  const int tid = threadIdx.x;
  const int lane = tid & 63;
  const int wave = tid >> 6;
  __shared__ int sp[NN];
  __shared__ unsigned hist[NBINS + 1];  // pos count low16 | neg count high16
  __shared__ unsigned wsum[16];
  __shared__ int sT[4];                 // Tp, Qp, Tn, Qn

  for (int i = tid; i < NBINS + 1; i += 1024) hist[i] = 0;
  if (tid == 0) { sT[0] = 0; sT[1] = 0; sT[2] = 0; sT[3] = 0; }
  __syncthreads();

  for (int i = tid; i < NN; i += 1024) {
    int p = packed[b * NN + i];
    sp[i] = p;
    int pm = p & 0x7FF, nm = (p >> 11) & 0x7FF;
    if (pm) atomicAdd(&hist[pm], 1u);
    if (nm) atomicAdd(&hist[nm], 0x10000u);
  }
  __syncthreads();

  // single-wave register suffix scan over 1280 bins (20 bins/lane, packed)
  if (wave == 0) {
    unsigned cs[21];
    const int base = 1 + lane * 20;
    cs[20] = 0;
    #pragma unroll
    for (int j = 19; j >= 0; --j) cs[j] = cs[j + 1] + hist[base + j];
    unsigned tot = cs[0];
    unsigned run = tot;
    #pragma unroll
    for (int off = 1; off < 64; off <<= 1) {
      unsigned u = __shfl_down(run, off);
      if (lane + off < 64) run += u;
    }
    unsigned above = run - tot;  // suffix over lanes > lane
    #pragma unroll
    for (int j = 0; j < 20; ++j) {
      int bin = base + j;
      unsigned s  = cs[j] + above;
      unsigned sn = cs[j + 1] + above;
      unsigned ps = s & 0xFFFFu, psn = sn & 0xFFFFu;
      if (ps >= NSEL && psn < NSEL) { sT[0] = bin; sT[1] = NSEL - (int)psn; }
      unsigned ns = s >> 16, nsn = sn >> 16;
      if (ns >= NSEL && nsn < NSEL) { sT[2] = bin; sT[3] = NSEL - (int)nsn; }
    }
  }
  __syncthreads();
  const int Tp = sT[0], Qp = sT[1], Tn = sT[2], Qn = sT[3];

  // tie-rank: thread t owns contiguous chunk [3t, 3t+3)
  const int n0 = tid * 3;
  int q[3] = {0, 0, 0};
  if (n0     < NN) q[0] = sp[n0];
  if (n0 + 1 < NN) q[1] = sp[n0 + 1];
  if (n0 + 2 < NN) q[2] = sp[n0 + 2];
  unsigned cc = 0;
  #pragma unroll
  for (int j = 0; j < 3; ++j) {
    int pm = q[j] & 0x7FF, nm = (q[j] >> 11) & 0x7FF;
    if (Tp && pm == Tp) cc += 1u;
    if (Tn && nm == Tn) cc += 0x10000u;
  }
  unsigned inc = cc;
  #pragma unroll
  for (int off = 1; off < 64; off <<= 1) {
    unsigned u = __shfl_up(inc, off);
    if (lane >= off) inc += u;
  }
  if (lane == 63) wsum[wave] = inc;
  __syncthreads();
  unsigned woff = 0;
  for (int w = 0; w < wave; ++w) woff += wsum[w];
  unsigned excl = woff + (inc - cc);
  int ep = (int)(excl & 0xFFFFu), en = (int)(excl >> 16);

  // selection + sparse scatter into pre-zeroed outputs
  #pragma unroll
  for (int j = 0; j < 3; ++j) {
    int n = n0 + j;
    if (n >= NN) break;
    int p = q[j];
    int pm = p & 0x7FF, nm = (p >> 11) & 0x7FF;
    bool selp;
    if (pm > Tp) selp = true;
    else if (pm && pm == Tp) { selp = (ep < Qp); ep++; }
    else selp = false;
    bool seln;
    if (nm > Tn) seln = true;
    else if (nm && nm == Tn) { seln = (en < Qn); en++; }
    else seln = false;
    if (selp | seln) {
      size_t nl = (size_t)b * NN + n;
      int lab = selp ? ((p >> 22) & 0x1F) : 0;
      out2[nl * 21 + lab] = 1.0f;
      if (lab > 0) out1[nl * 21 + lab] = deltas[nl];
    }
  }
}

extern "C" void kernel_launch(void* const* d_in, const int* in_sizes, int n_in,
                              void* d_out, int out_size, void* d_ws, size_t ws_size,
                              hipStream_t stream) {
  const float4* roi = (const float4*)d_in[0];
  const float4* gt  = (const float4*)d_in[1];
  const int* gtl  = (const int*)d_in[2];
  const int* rpos = (const int*)d_in[3];
  const int* rneg = (const int*)d_in[4];

  char* ws = (char*)d_ws;
  int*    packed = (int*)ws;                    // B*N ints (768 KB)
  float4* deltas = (float4*)(ws + (1 << 20));   // B*N float4 (3 MB)

  float4* out1 = (float4*)d_out;                            // B*N*21 float4
  float*  out2 = (float*)d_out + (size_t)BB * NN * 21 * 4;  // B*N*21 floats

  kA<<<ZB + CB, 256, 0, stream>>>(roi, gt, gtl, rpos, rneg, packed, deltas,
                                  (float4*)d_out);
  kB<<<BB, 1024, 0, stream>>>(packed, deltas, out1, out2);
}